// Round 4
// baseline (559.611 us; speedup 1.0000x reference)
//
#include <hip/hip_runtime.h>

// GAT 2-layer, N=100000, E=1600000 (+N self loops), 128 -> 4x32 -> 4x32
#define NN 100000
#define EE 1600000
#define ET (NN + EE)
#define NPAD 114688   // NN rounded up to 7*16384 for unguarded scan loads
#define NPASS 8
#define DRANGE ((NN + NPASS - 1) / NPASS)   // 12500

__device__ __forceinline__ float leaky(float x) { return x > 0.f ? x : 0.2f * x; }

// pack two floats to bf16 pair (RNE), low = a, high = b
__device__ __forceinline__ unsigned int bfpack2(float a, float b)
{
    unsigned int xa = __float_as_uint(a), xb = __float_as_uint(b);
    xa = (xa + 0x7fffu + ((xa >> 16) & 1u)) >> 16;
    xb = (xb + 0x7fffu + ((xb >> 16) & 1u)) & 0xffff0000u;
    return xa | xb;
}

// ---------------- CSR build ----------------

__global__ __launch_bounds__(256) void hist_kernel(const int* __restrict__ dst, int* __restrict__ cnt)
{
    const int tid0 = blockIdx.x * 256 + threadIdx.x;
    const int nthr = gridDim.x * 256;
    for (int e4 = tid0 * 4; e4 < EE; e4 += nthr * 4) {
        int4 dv = *(const int4*)&dst[e4];
        atomicAdd(&cnt[dv.x], 1);
        atomicAdd(&cnt[dv.y], 1);
        atomicAdd(&cnt[dv.z], 1);
        atomicAdd(&cnt[dv.w], 1);
    }
}

// single-block scan, 1024 thr x 16 elem = 16384/iter, 7 iters (cnt padded with zeros)
// adds +1 per valid node for the self-loop
__global__ __launch_bounds__(1024) void scan_kernel(const int* __restrict__ cnt, int* __restrict__ rowptr)
{
    __shared__ int wsum[16];
    __shared__ int tot;
    const int t = threadIdx.x, lane = t & 63, w = t >> 6;
    int carry = 0;
    for (int base = 0; base < NN; base += 16384) {
        const int idx = base + t * 16;
        int v[16];
        #pragma unroll
        for (int j = 0; j < 4; j++)
            *(int4*)&v[j * 4] = *(const int4*)&cnt[idx + j * 4];
        #pragma unroll
        for (int j = 0; j < 16; j++) v[j] += (idx + j < NN) ? 1 : 0;   // self-loop
        int s = 0;
        #pragma unroll
        for (int j = 0; j < 16; j++) s += v[j];
        int sc = s;
        #pragma unroll
        for (int off = 1; off < 64; off <<= 1) {
            int u = __shfl_up(sc, off);
            if (lane >= off) sc += u;
        }
        if (lane == 63) wsum[w] = sc;
        __syncthreads();
        if (t == 0) {
            int a = 0;
            for (int i = 0; i < 16; i++) { int xch = wsum[i]; wsum[i] = a; a += xch; }
            tot = a;
        }
        __syncthreads();
        int run = carry + wsum[w] + (sc - s);
        #pragma unroll
        for (int j = 0; j < 16; j++) {
            if (idx + j < NN) rowptr[idx + j] = run;
            run += v[j];
        }
        carry += tot;
        __syncthreads();
    }
    if (t == 0) rowptr[NN] = carry;
}

// dst-range passes: each pass's CSR target slice (~850KB) stays L2-resident,
// eliminating the 64B/write allocate round-trip of fully-random 4B scatters.
__global__ __launch_bounds__(256) void scatter_kernel(const int* __restrict__ src, const int* __restrict__ dst,
                                                      const int* __restrict__ rowptr, int* __restrict__ cur,
                                                      int* __restrict__ csr)
{
    const int tid0 = blockIdx.x * 256 + threadIdx.x;
    const int nthr = gridDim.x * 256;
    for (int pass = 0; pass < NPASS; ++pass) {
        const int dlo = pass * DRANGE;
        const int dhi = min(NN, dlo + DRANGE);
        for (int e4 = tid0 * 4; e4 < EE; e4 += nthr * 4) {
            int4 dv = *(const int4*)&dst[e4];
            #pragma unroll
            for (int j = 0; j < 4; ++j) {
                int d = (&dv.x)[j];
                if (d >= dlo && d < dhi) {
                    int s = src[e4 + j];
                    int pos = atomicAdd(&cur[d], 1);
                    csr[rowptr[d] + pos] = s;
                }
            }
        }
        // self-loop for nodes in this pass's range
        for (int d = dlo + tid0; d < dhi; d += nthr) {
            int pos = atomicAdd(&cur[d], 1);
            csr[rowptr[d] + pos] = d;
        }
    }
}

// ---------------- GEMM + fused logits: Hbf = bf16(X @ W), al = (X@W)·att  ----------------

__global__ __launch_bounds__(256) void gemm_kernel(const float* __restrict__ X, const float* __restrict__ W,
                                                   const float* __restrict__ att_src, const float* __restrict__ att_dst,
                                                   unsigned int* __restrict__ Hbf,   // [N][64] packed bf16x2
                                                   float* __restrict__ alS, float* __restrict__ alD, int nrows)
{
    __shared__ float wlds[128 * 128];   // 64 KB
    __shared__ float xlds[64 * 32];     // 8 KB k-chunk staging
    const int t = threadIdx.x;
    #pragma unroll
    for (int i = 0; i < 16; i++) {
        int f4 = t + i * 256;
        ((float4*)wlds)[f4] = ((const float4*)W)[f4];
    }
    const int tx = t % 32;  // cols 4*tx .. 4*tx+3
    const int ty = t / 32;  // rows ty + 8*i
    const int head = tx >> 3;
    const float4 asv = *(const float4*)&att_src[tx * 4];
    const float4 adv = *(const float4*)&att_dst[tx * 4];
    const int ntiles = (nrows + 63) / 64;
    for (int tile = blockIdx.x; tile < ntiles; tile += gridDim.x) {
        const int r0 = tile * 64;
        float acc[8][4] = {};
        for (int kc = 0; kc < 128; kc += 32) {
            __syncthreads();
            #pragma unroll
            for (int j = 0; j < 2; j++) {
                int f4 = t + j * 256;          // 0..511
                int row = f4 >> 3;             // 8 float4 per row
                int kk = (f4 & 7) * 4;
                float4 v = make_float4(0.f, 0.f, 0.f, 0.f);
                if (r0 + row < nrows) v = *(const float4*)&X[(size_t)(r0 + row) * 128 + kc + kk];
                *(float4*)&xlds[row * 32 + kk] = v;
            }
            __syncthreads();
            #pragma unroll
            for (int kk = 0; kk < 32; kk += 4) {
                float4 w0 = *(float4*)&wlds[(kc + kk + 0) * 128 + tx * 4];
                float4 w1 = *(float4*)&wlds[(kc + kk + 1) * 128 + tx * 4];
                float4 w2 = *(float4*)&wlds[(kc + kk + 2) * 128 + tx * 4];
                float4 w3 = *(float4*)&wlds[(kc + kk + 3) * 128 + tx * 4];
                #pragma unroll
                for (int i = 0; i < 8; i++) {
                    float4 xv = *(float4*)&xlds[(ty + 8 * i) * 32 + kk];
                    acc[i][0] += xv.x * w0.x + xv.y * w1.x + xv.z * w2.x + xv.w * w3.x;
                    acc[i][1] += xv.x * w0.y + xv.y * w1.y + xv.z * w2.y + xv.w * w3.y;
                    acc[i][2] += xv.x * w0.z + xv.y * w1.z + xv.z * w2.z + xv.w * w3.z;
                    acc[i][3] += xv.x * w0.w + xv.y * w1.w + xv.z * w2.w + xv.w * w3.w;
                }
            }
        }
        #pragma unroll
        for (int i = 0; i < 8; i++) {
            int r = r0 + ty + 8 * i;
            if (r < nrows) {
                uint2 wv;
                wv.x = bfpack2(acc[i][0], acc[i][1]);
                wv.y = bfpack2(acc[i][2], acc[i][3]);
                *(uint2*)&Hbf[(size_t)r * 64 + tx * 2] = wv;
                float ps = acc[i][0] * asv.x + acc[i][1] * asv.y + acc[i][2] * asv.z + acc[i][3] * asv.w;
                float pd = acc[i][0] * adv.x + acc[i][1] * adv.y + acc[i][2] * adv.z + acc[i][3] * adv.w;
                #pragma unroll
                for (int off = 1; off <= 4; off <<= 1) {
                    ps += __shfl_xor(ps, off);
                    pd += __shfl_xor(pd, off);
                }
                if ((tx & 7) == 0) {
                    alS[r * 4 + head] = ps;
                    alD[r * 4 + head] = pd;
                }
            }
        }
    }
}

// ---------------- fused softmax(no-max) + aggregate, one wave per dst node ----------------

__global__ __launch_bounds__(256) void agg_kernel(const unsigned int* __restrict__ Hbf,
                                                  const int* __restrict__ rowptr, const int* __restrict__ csr,
                                                  const float* __restrict__ alS, const float* __restrict__ alD,
                                                  float* __restrict__ OUT, int do_relu)
{
    __shared__ float pl[4][64 * 4];
    __shared__ int   sl[4][64];
    const int w = threadIdx.x >> 6, lane = threadIdx.x & 63;
    const int wid = (blockIdx.x * 256 + threadIdx.x) >> 6;   // dst node
    if (wid >= NN) return;
    const int s0 = rowptr[wid], s1 = rowptr[wid + 1];
    const float4 ad = *(const float4*)&alD[wid * 4];
    const int hq = lane >> 4;                                 // head of this lane
    const unsigned int* __restrict__ Hl = Hbf + lane;         // lane's 2 channels (4B)

    float2 acc = make_float2(0.f, 0.f);
    float den = 0.f;
    for (int base = s0; base < s1; base += 64) {
        const int nthis = min(64, s1 - base);
        // phase A: lane-parallel p computation for this chunk
        if (lane < nthis) {
            int s = csr[base + lane];
            float4 as = *(const float4*)&alS[s * 4];
            float4 p;
            p.x = __expf(leaky(as.x + ad.x));
            p.y = __expf(leaky(as.y + ad.y));
            p.z = __expf(leaky(as.z + ad.z));
            p.w = __expf(leaky(as.w + ad.w));
            *(float4*)&pl[w][lane * 4] = p;
            sl[w][lane] = s;
        }
        // same-wave LDS write/read; compiler inserts lgkmcnt wait, no barrier needed
        int k = 0;
        for (; k + 2 <= nthis; k += 2) {
            float pa = pl[w][k * 4 + hq];
            float pb = pl[w][k * 4 + 4 + hq];
            int sa = sl[w][k];
            int sb = sl[w][k + 1];
            unsigned int ua = Hl[(size_t)sa * 64];
            unsigned int ub = Hl[(size_t)sb * 64];
            den += pa + pb;
            acc.x += pa * __uint_as_float(ua << 16);
            acc.y += pa * __uint_as_float(ua & 0xffff0000u);
            acc.x += pb * __uint_as_float(ub << 16);
            acc.y += pb * __uint_as_float(ub & 0xffff0000u);
        }
        if (k < nthis) {
            float pa = pl[w][k * 4 + hq];
            int sa = sl[w][k];
            unsigned int ua = Hl[(size_t)sa * 64];
            den += pa;
            acc.x += pa * __uint_as_float(ua << 16);
            acc.y += pa * __uint_as_float(ua & 0xffff0000u);
        }
    }
    float inv = 1.f / (den + 1e-16f);
    float o0 = acc.x * inv, o1 = acc.y * inv;
    if (do_relu) { o0 = fmaxf(o0, 0.f); o1 = fmaxf(o1, 0.f); }
    ((float2*)OUT)[(size_t)wid * 64 + lane] = make_float2(o0, o1);
}

// ---------------- launch ----------------

extern "C" void kernel_launch(void* const* d_in, const int* in_sizes, int n_in,
                              void* d_out, int out_size, void* d_ws, size_t ws_size,
                              hipStream_t stream)
{
    const float* x   = (const float*)d_in[0];
    const int*   ei  = (const int*)d_in[1];      // [2][E] int32
    const float* W1  = (const float*)d_in[2];
    const float* as1 = (const float*)d_in[3];
    const float* ad1 = (const float*)d_in[4];
    const float* W2  = (const float*)d_in[5];
    const float* as2 = (const float*)d_in[6];
    const float* ad2 = (const float*)d_in[7];
    const int* srcp = ei;
    const int* dstp = ei + EE;

    char* w = (char*)d_ws;
    float* hB  = (float*)w;         w += (size_t)NN * 128 * 4;   // layer-1 output (fp32)
    unsigned int* Hbf = (unsigned int*)w; w += (size_t)NN * 64 * 4; // packed bf16 H
    float* alS = (float*)w; w += (size_t)NN * 4 * 4;
    float* alD = (float*)w; w += (size_t)NN * 4 * 4;
    int* rowptr = (int*)w;  w += (size_t)(NN + 1) * 4;
    int* cnt    = (int*)w;  w += (size_t)NPAD * 4;
    int* csr    = (int*)w;  w += (size_t)ET * 4;

    // ---- CSR build (reused by both layers) ----
    hipMemsetAsync(cnt, 0, NPAD * sizeof(int), stream);
    hist_kernel<<<1563, 256, 0, stream>>>(dstp, cnt);
    scan_kernel<<<1, 1024, 0, stream>>>(cnt, rowptr);
    hipMemsetAsync(cnt, 0, NN * sizeof(int), stream);
    scatter_kernel<<<1563, 256, 0, stream>>>(srcp, dstp, rowptr, cnt, csr);

    const int gemm_blocks = (NN + 63) / 64;      // 1563
    const int node_wave_blocks = (NN + 3) / 4;   // 25000

    // ---- layer 1 ----
    gemm_kernel<<<gemm_blocks, 256, 0, stream>>>(x, W1, as1, ad1, Hbf, alS, alD, NN);
    agg_kernel<<<node_wave_blocks, 256, 0, stream>>>(Hbf, rowptr, csr, alS, alD, hB, 1);

    // ---- layer 2 ----
    gemm_kernel<<<gemm_blocks, 256, 0, stream>>>(hB, W2, as2, ad2, Hbf, alS, alD, NN);
    agg_kernel<<<node_wave_blocks, 256, 0, stream>>>(Hbf, rowptr, csr, alS, alD, (float*)d_out, 0);
}

// Round 5
// 415.427 us; speedup vs baseline: 1.3471x; 1.3471x over previous
//
#include <hip/hip_runtime.h>

// GAT 2-layer, N=100000, E=1600000 (+N self loops), 128 -> 4x32 -> 4x32
#define NN 100000
#define EE 1600000
#define ET (NN + EE)
#define NPAD 114688   // NN rounded up to 7*16384 for unguarded scan loads
#define NPASS 8
#define DRANGE ((NN + NPASS - 1) / NPASS)   // 12500
#define NROWPAD 100032   // 1563 * 64, zero-padded rows for unguarded MFMA A-loads
#define NTILES 1563

typedef short bf16x8 __attribute__((ext_vector_type(8)));
typedef float f32x4 __attribute__((ext_vector_type(4)));

__device__ __forceinline__ float leaky(float x) { return x > 0.f ? x : 0.2f * x; }

// pack two floats to bf16 pair (RNE), low = a, high = b
__device__ __forceinline__ unsigned int bfpack2(float a, float b)
{
    unsigned int xa = __float_as_uint(a), xb = __float_as_uint(b);
    xa = (xa + 0x7fffu + ((xa >> 16) & 1u)) >> 16;
    xb = (xb + 0x7fffu + ((xb >> 16) & 1u)) & 0xffff0000u;
    return xa | xb;
}

__device__ __forceinline__ unsigned short bf1(float a)
{
    unsigned int x = __float_as_uint(a);
    return (unsigned short)((x + 0x7fffu + ((x >> 16) & 1u)) >> 16);
}

// ---------------- input prep: fp32 -> packed bf16 ----------------

// Xbf[NROWPAD][128] bf16 (as uint pairs); pad rows zeroed. Also zeroes Xbf2's pad rows.
__global__ __launch_bounds__(256) void prep_x(const float* __restrict__ X,
                                              unsigned int* __restrict__ Xbf,
                                              unsigned int* __restrict__ Xbf2)
{
    const int tid0 = blockIdx.x * 256 + threadIdx.x;
    const int nthr = gridDim.x * 256;
    const int total = NROWPAD * 16;          // uint4 per row = 16
    for (int i = tid0; i < total; i += nthr) {
        int row = i >> 4, inner = i & 15;
        uint4 o;
        if (row < NN) {
            const float* p = X + (size_t)row * 128 + inner * 8;
            float4 f0 = *(const float4*)p;
            float4 f1 = *(const float4*)(p + 4);
            o.x = bfpack2(f0.x, f0.y); o.y = bfpack2(f0.z, f0.w);
            o.z = bfpack2(f1.x, f1.y); o.w = bfpack2(f1.z, f1.w);
        } else {
            o = make_uint4(0, 0, 0, 0);
            *(uint4*)&Xbf2[(size_t)i * 4] = o;    // keep layer-2 input pad deterministic
        }
        *(uint4*)&Xbf[(size_t)i * 4] = o;
    }
}

// Wtb[col][k] = bf16(W[k][col]) for both layers (each 128x128)
__global__ __launch_bounds__(256) void prep_w(const float* __restrict__ W1, const float* __restrict__ W2,
                                              unsigned short* __restrict__ Wtb1, unsigned short* __restrict__ Wtb2)
{
    int tid = blockIdx.x * 256 + threadIdx.x;   // 32 blocks -> 8192 threads, 2*128*32
    int layer = tid >> 12;
    int rem = tid & 4095;
    int c = rem >> 5;
    int kq = (rem & 31) * 4;
    const float* Ws = layer ? W2 : W1;
    unsigned short* Wd = layer ? Wtb2 : Wtb1;
    ushort4 o;
    o.x = bf1(Ws[(kq + 0) * 128 + c]);
    o.y = bf1(Ws[(kq + 1) * 128 + c]);
    o.z = bf1(Ws[(kq + 2) * 128 + c]);
    o.w = bf1(Ws[(kq + 3) * 128 + c]);
    *(ushort4*)&Wd[c * 128 + kq] = o;
}

// ---------------- CSR build ----------------

__global__ __launch_bounds__(256) void hist_kernel(const int* __restrict__ dst, int* __restrict__ cnt)
{
    const int tid0 = blockIdx.x * 256 + threadIdx.x;
    const int nthr = gridDim.x * 256;
    for (int e4 = tid0 * 4; e4 < EE; e4 += nthr * 4) {
        int4 dv = *(const int4*)&dst[e4];
        atomicAdd(&cnt[dv.x], 1);
        atomicAdd(&cnt[dv.y], 1);
        atomicAdd(&cnt[dv.z], 1);
        atomicAdd(&cnt[dv.w], 1);
    }
}

__global__ __launch_bounds__(1024) void scan_kernel(const int* __restrict__ cnt, int* __restrict__ rowptr)
{
    __shared__ int wsum[16];
    __shared__ int tot;
    const int t = threadIdx.x, lane = t & 63, w = t >> 6;
    int carry = 0;
    for (int base = 0; base < NN; base += 16384) {
        const int idx = base + t * 16;
        int v[16];
        #pragma unroll
        for (int j = 0; j < 4; j++)
            *(int4*)&v[j * 4] = *(const int4*)&cnt[idx + j * 4];
        #pragma unroll
        for (int j = 0; j < 16; j++) v[j] += (idx + j < NN) ? 1 : 0;   // self-loop
        int s = 0;
        #pragma unroll
        for (int j = 0; j < 16; j++) s += v[j];
        int sc = s;
        #pragma unroll
        for (int off = 1; off < 64; off <<= 1) {
            int u = __shfl_up(sc, off);
            if (lane >= off) sc += u;
        }
        if (lane == 63) wsum[w] = sc;
        __syncthreads();
        if (t == 0) {
            int a = 0;
            for (int i = 0; i < 16; i++) { int xch = wsum[i]; wsum[i] = a; a += xch; }
            tot = a;
        }
        __syncthreads();
        int run = carry + wsum[w] + (sc - s);
        #pragma unroll
        for (int j = 0; j < 16; j++) {
            if (idx + j < NN) rowptr[idx + j] = run;
            run += v[j];
        }
        carry += tot;
        __syncthreads();
    }
    if (t == 0) rowptr[NN] = carry;
}

// dst-range passes keep each pass's CSR slice L2-resident (no 64B write-allocate churn)
__global__ __launch_bounds__(256) void scatter_kernel(const int* __restrict__ src, const int* __restrict__ dst,
                                                      const int* __restrict__ rowptr, int* __restrict__ cur,
                                                      int* __restrict__ csr)
{
    const int tid0 = blockIdx.x * 256 + threadIdx.x;
    const int nthr = gridDim.x * 256;
    for (int pass = 0; pass < NPASS; ++pass) {
        const int dlo = pass * DRANGE;
        const int dhi = min(NN, dlo + DRANGE);
        for (int e4 = tid0 * 4; e4 < EE; e4 += nthr * 4) {
            int4 dv = *(const int4*)&dst[e4];
            #pragma unroll
            for (int j = 0; j < 4; ++j) {
                int d = (&dv.x)[j];
                if (d >= dlo && d < dhi) {
                    int s = src[e4 + j];
                    int pos = atomicAdd(&cur[d], 1);
                    csr[rowptr[d] + pos] = s;
                }
            }
        }
        for (int d = dlo + tid0; d < dhi; d += nthr) {
            int pos = atomicAdd(&cur[d], 1);
            csr[rowptr[d] + pos] = d;
        }
    }
}

// ---------------- MFMA GEMM + fused logits ----------------
// H = Xbf @ W (bf16 in, fp32 acc), Hbf packed bf16 out, alS/alD per-head logits.
// B (W) fragments are tile-invariant -> register-resident (8 col-tiles x 4 k-steps).
// No LDS, no barriers. A-loads stream from L3-resident Xbf.

__global__ __launch_bounds__(256) void gemm_mfma(const unsigned short* __restrict__ Xbf,
                                                 const unsigned short* __restrict__ Wtb,
                                                 const float* __restrict__ att_src,
                                                 const float* __restrict__ att_dst,
                                                 unsigned int* __restrict__ Hbf,
                                                 float* __restrict__ alS, float* __restrict__ alD)
{
    const int w = threadIdx.x >> 6, lane = threadIdx.x & 63;
    const int cl = lane & 15, b = lane >> 4;

    // register-resident B fragments: B[k][col], col = cl, k-slice 32s + 8b + [0..7]
    bf16x8 Bf[8][4];
    #pragma unroll
    for (int c = 0; c < 8; c++)
        #pragma unroll
        for (int s = 0; s < 4; s++)
            Bf[c][s] = *(const bf16x8*)(Wtb + (16 * c + cl) * 128 + 32 * s + 8 * b);

    float asv[8], adv[8];
    #pragma unroll
    for (int c = 0; c < 8; c++) { asv[c] = att_src[16 * c + cl]; adv[c] = att_dst[16 * c + cl]; }

    for (int tile = blockIdx.x; tile < NTILES; tile += gridDim.x) {
        const int rowb = tile * 64 + 16 * w;
        // A fragments: row = cl, same (b, elem) -> k map as B
        const unsigned short* pa = Xbf + (size_t)(rowb + cl) * 128 + 8 * b;
        bf16x8 Af[4];
        #pragma unroll
        for (int s = 0; s < 4; s++) Af[s] = *(const bf16x8*)(pa + 32 * s);

        f32x4 acc[8];
        #pragma unroll
        for (int c = 0; c < 8; c++) acc[c] = (f32x4){0.f, 0.f, 0.f, 0.f};
        #pragma unroll
        for (int s = 0; s < 4; s++)
            #pragma unroll
            for (int c = 0; c < 8; c++)
                acc[c] = __builtin_amdgcn_mfma_f32_16x16x32_bf16(Af[s], Bf[c][s], acc[c], 0, 0, 0);

        // ---- epilogue. C/D: col = cl (within tile c), row = rowb + 4b + r ----
        const int row0 = rowb + 4 * b;
        #pragma unroll
        for (int c = 0; c < 8; c++) {
            #pragma unroll
            for (int r = 0; r < 4; r++) {
                float partner = __shfl_xor(acc[c][r], 1);
                if (!(cl & 1) && row0 + r < NN)
                    Hbf[(size_t)(row0 + r) * 64 + 8 * c + (cl >> 1)] = bfpack2(acc[c][r], partner);
            }
        }
        #pragma unroll
        for (int r = 0; r < 4; r++) {
            float ps0 = 0, ps1 = 0, ps2 = 0, ps3 = 0;
            float pd0 = 0, pd1 = 0, pd2 = 0, pd3 = 0;
            #pragma unroll
            for (int c = 0; c < 8; c++) {
                float v = acc[c][r];
                if (c < 2)      { ps0 += v * asv[c]; pd0 += v * adv[c]; }
                else if (c < 4) { ps1 += v * asv[c]; pd1 += v * adv[c]; }
                else if (c < 6) { ps2 += v * asv[c]; pd2 += v * adv[c]; }
                else            { ps3 += v * asv[c]; pd3 += v * adv[c]; }
            }
            // head-multiplexed butterfly over the 16 lanes of this row group:
            // lane cl ends owning head (cl&3) summed over all 16 lanes
            float t0 = ps0 + __shfl_xor(ps0, 1);
            float t1 = ps1 + __shfl_xor(ps1, 1);
            float t2 = ps2 + __shfl_xor(ps2, 1);
            float t3 = ps3 + __shfl_xor(ps3, 1);
            float a0 = (cl & 1) ? t1 : t0;
            float a1 = (cl & 1) ? t3 : t2;
            a0 += __shfl_xor(a0, 2);
            a1 += __shfl_xor(a1, 2);
            float av = (cl & 2) ? a1 : a0;
            av += __shfl_xor(av, 4);
            av += __shfl_xor(av, 8);
            t0 = pd0 + __shfl_xor(pd0, 1);
            t1 = pd1 + __shfl_xor(pd1, 1);
            t2 = pd2 + __shfl_xor(pd2, 1);
            t3 = pd3 + __shfl_xor(pd3, 1);
            a0 = (cl & 1) ? t1 : t0;
            a1 = (cl & 1) ? t3 : t2;
            a0 += __shfl_xor(a0, 2);
            a1 += __shfl_xor(a1, 2);
            float dv = (cl & 2) ? a1 : a0;
            dv += __shfl_xor(dv, 4);
            dv += __shfl_xor(dv, 8);
            if (cl < 4 && row0 + r < NN) {
                alS[(row0 + r) * 4 + cl] = av;
                alD[(row0 + r) * 4 + cl] = dv;
            }
        }
    }
}

// ---------------- fused softmax(no-max) + aggregate, one wave per dst node ----------------

__global__ __launch_bounds__(256) void agg_kernel(const unsigned int* __restrict__ Hbf,
                                                  const int* __restrict__ rowptr, const int* __restrict__ csr,
                                                  const float* __restrict__ alS, const float* __restrict__ alD,
                                                  float* __restrict__ OUTf, unsigned int* __restrict__ OUTb,
                                                  int do_relu)
{
    __shared__ float pl[4][64 * 4];
    __shared__ int   sl[4][64];
    const int w = threadIdx.x >> 6, lane = threadIdx.x & 63;
    const int wid = (blockIdx.x * 256 + threadIdx.x) >> 6;   // dst node
    if (wid >= NN) return;
    const int s0 = rowptr[wid], s1 = rowptr[wid + 1];
    const float4 ad = *(const float4*)&alD[wid * 4];
    const int hq = lane >> 4;                                 // head of this lane
    const unsigned int* __restrict__ Hl = Hbf + lane;         // lane's 2 channels (4B)

    float2 acc = make_float2(0.f, 0.f);
    float den = 0.f;
    for (int base = s0; base < s1; base += 64) {
        const int nthis = min(64, s1 - base);
        if (lane < nthis) {
            int s = csr[base + lane];
            float4 as = *(const float4*)&alS[s * 4];
            float4 p;
            p.x = __expf(leaky(as.x + ad.x));
            p.y = __expf(leaky(as.y + ad.y));
            p.z = __expf(leaky(as.z + ad.z));
            p.w = __expf(leaky(as.w + ad.w));
            *(float4*)&pl[w][lane * 4] = p;
            sl[w][lane] = s;
        }
        // same-wave LDS write/read; compiler inserts lgkmcnt wait, no barrier needed
        int k = 0;
        for (; k + 2 <= nthis; k += 2) {
            float pa = pl[w][k * 4 + hq];
            float pb = pl[w][k * 4 + 4 + hq];
            int sa = sl[w][k];
            int sb = sl[w][k + 1];
            unsigned int ua = Hl[(size_t)sa * 64];
            unsigned int ub = Hl[(size_t)sb * 64];
            den += pa + pb;
            acc.x += pa * __uint_as_float(ua << 16);
            acc.y += pa * __uint_as_float(ua & 0xffff0000u);
            acc.x += pb * __uint_as_float(ub << 16);
            acc.y += pb * __uint_as_float(ub & 0xffff0000u);
        }
        if (k < nthis) {
            float pa = pl[w][k * 4 + hq];
            int sa = sl[w][k];
            unsigned int ua = Hl[(size_t)sa * 64];
            den += pa;
            acc.x += pa * __uint_as_float(ua << 16);
            acc.y += pa * __uint_as_float(ua & 0xffff0000u);
        }
    }
    float inv = 1.f / (den + 1e-16f);
    float o0 = acc.x * inv, o1 = acc.y * inv;
    if (do_relu) { o0 = fmaxf(o0, 0.f); o1 = fmaxf(o1, 0.f); }
    if (OUTb) OUTb[(size_t)wid * 64 + lane] = bfpack2(o0, o1);
    else ((float2*)OUTf)[(size_t)wid * 64 + lane] = make_float2(o0, o1);
}

// ---------------- launch ----------------

extern "C" void kernel_launch(void* const* d_in, const int* in_sizes, int n_in,
                              void* d_out, int out_size, void* d_ws, size_t ws_size,
                              hipStream_t stream)
{
    const float* x   = (const float*)d_in[0];
    const int*   ei  = (const int*)d_in[1];      // [2][E] int32
    const float* W1  = (const float*)d_in[2];
    const float* as1 = (const float*)d_in[3];
    const float* ad1 = (const float*)d_in[4];
    const float* W2  = (const float*)d_in[5];
    const float* as2 = (const float*)d_in[6];
    const float* ad2 = (const float*)d_in[7];
    const int* srcp = ei;
    const int* dstp = ei + EE;

    char* w = (char*)d_ws;
    unsigned int* Xbf  = (unsigned int*)w; w += (size_t)NROWPAD * 64 * 4;   // layer-1 input bf16
    unsigned int* Xbf2 = (unsigned int*)w; w += (size_t)NROWPAD * 64 * 4;   // layer-2 input bf16
    unsigned int* Hbf  = (unsigned int*)w; w += (size_t)NN * 64 * 4;        // per-layer H bf16
    unsigned short* Wtb1 = (unsigned short*)w; w += 16384 * 2;
    unsigned short* Wtb2 = (unsigned short*)w; w += 16384 * 2;
    float* alS = (float*)w; w += (size_t)NN * 4 * 4;
    float* alD = (float*)w; w += (size_t)NN * 4 * 4;
    int* rowptr = (int*)w;  w += (size_t)(NN + 1) * 4;
    int* cnt    = (int*)w;  w += (size_t)NPAD * 4;
    int* csr    = (int*)w;  w += (size_t)ET * 4;

    // ---- prep (bf16 conversions, W transpose) ----
    prep_x<<<1024, 256, 0, stream>>>(x, Xbf, Xbf2);
    prep_w<<<32, 256, 0, stream>>>(W1, W2, Wtb1, Wtb2);

    // ---- CSR build (reused by both layers) ----
    hipMemsetAsync(cnt, 0, NPAD * sizeof(int), stream);
    hist_kernel<<<1563, 256, 0, stream>>>(dstp, cnt);
    scan_kernel<<<1, 1024, 0, stream>>>(cnt, rowptr);
    hipMemsetAsync(cnt, 0, NN * sizeof(int), stream);
    scatter_kernel<<<1563, 256, 0, stream>>>(srcp, dstp, rowptr, cnt, csr);

    const int node_wave_blocks = (NN + 3) / 4;   // 25000

    // ---- layer 1 ----
    gemm_mfma<<<512, 256, 0, stream>>>((const unsigned short*)Xbf, Wtb1, as1, ad1, Hbf, alS, alD);
    agg_kernel<<<node_wave_blocks, 256, 0, stream>>>(Hbf, rowptr, csr, alS, alD, nullptr, Xbf2, 1);

    // ---- layer 2 ----
    gemm_mfma<<<512, 256, 0, stream>>>((const unsigned short*)Xbf2, Wtb2, as2, ad2, Hbf, alS, alD);
    agg_kernel<<<node_wave_blocks, 256, 0, stream>>>(Hbf, rowptr, csr, alS, alD, (float*)d_out, nullptr, 0);
}